// Round 7
// baseline (496.471 us; speedup 1.0000x reference)
//
#include <hip/hip_runtime.h>

typedef __attribute__((ext_vector_type(8))) short short8;
typedef __attribute__((ext_vector_type(4))) short short4v;
typedef __attribute__((ext_vector_type(4))) float float4v;
typedef unsigned short ushort_t;
typedef __bf16 bf16_t;

#define MFMA16(A,B,C) __builtin_amdgcn_mfma_f32_16x16x32_bf16((A),(B),(C),0,0,0)
#define LOG2E 1.4426950408889634f

// ---- workspace layout (written once by prep_rel, read by every block) ----
// [0,10240):     EQKH 256 x 40B rows [t]: rel_hi[i]*log2e at [0,32), pad [32,40)
// [10240,20480): EQKL same for lo residuals
// [20480,29440): EVR 16 x 560B rows [i]: rel_v bf16 at t in [0,280) (t>=255 -> 0)
#define WS_BYTES 29440

// ---- LDS layout ----
// EQKH: 256 x 40B [t] (stride 40 = 10 dw -> 2-way max on b64 reads)
// EQKL: 256 x 40B
// W:    WH 32 x 272B at 20480, WL at 29184 (live P0..P1-mainloop only)
// QH:   128 x 48B [d] at 20480 (aliases dead W after mid-P1 barrier):
//       [0,32) qk-hi (o<8 q*scale, o in [8,16) k), [32,48) k*log2e (dots B)
// QL:   128 x 40B [d] at 26624: qk-lo residuals
// ATT:  128 x 288B [d] at 0 (aliases EQK/QH/QL after score barrier):
//       bf16 UNNORMALIZED e over skewed tt in [0,144), tt = j + 15 - (d&15);
//       byte addr XOR-swizzled by ((d>>2)&3)<<4 (bijective; 4*288 % 64 == 0)
// EVR:  16 x 560B [i] at 37888: rel_v bf16 (t = tt + toff)
// V:    16 x 272B [i] at 46848: v[i][d] bf16
// IB:   32 x {inv, b0} f32 at 51200
#define OFF_EQKH 0
#define OFF_EQKL 10240
#define OFF_WH   20480
#define OFF_WL   29184
#define OFF_QH   20480
#define OFF_QL   26624
#define OFF_ATT  0
#define OFF_EVR  37888
#define OFF_V    46848
#define OFF_IB   51200
#define LDS_BYTES 51456     // <= 54613 -> 3 blocks/CU

__device__ __forceinline__ ushort_t f2bf(float f) {
  return __builtin_bit_cast(ushort_t, (bf16_t)f);   // HW RNE cvt
}
__device__ __forceinline__ float bf2f(ushort_t s) {
  return __builtin_bit_cast(float, ((unsigned)s) << 16);
}
__device__ __forceinline__ short8 ld8_2x4(const char* p) {  // two b64 reads (8B-aligned rows)
  short4v a = *(const short4v*)p;
  short4v b = *(const short4v*)(p + 8);
  return (short8){a[0],a[1],a[2],a[3],b[0],b[1],b[2],b[3]};
}
__device__ __forceinline__ short8 sel8(bool c, short8 a) {
  short8 r;
  #pragma unroll
  for (int k = 0; k < 8; ++k) r[k] = c ? a[k] : (short)0;
  return r;
}

// ---------- pre-kernel: block-invariant rel tables into workspace ----------
__global__ __launch_bounds__(512) void prep_rel(const float* __restrict__ relg,
                                                char* __restrict__ ws) {
  int idx = blockIdx.x * 512 + threadIdx.x;
  if (idx < 4096) {
    int i = idx & 15, t = idx >> 4;
    float r1 = 0.f;
    if (t < 255) r1 = relg[i * 255 + (254 - t)] * LOG2E;
    ushort_t h1 = f2bf(r1);
    *(ushort_t*)(ws + t * 40 + i * 2)         = h1;
    *(ushort_t*)(ws + 10240 + t * 40 + i * 2) = f2bf(r1 - bf2f(h1));
  } else if (idx < 8576) {
    int k = idx - 4096;                 // i*280 + c
    int i = k / 280, c = k - i * 280;
    float r2 = 0.f;
    if (c < 255) r2 = relg[(16 + i) * 255 + (254 - c)];
    *(ushort_t*)(ws + 20480 + i * 560 + c * 2) = f2bf(r2);
  }
}

__global__ __launch_bounds__(512, 6) void axial_fused(
    const float* __restrict__ xg,      // (2048,128,128) f32
    const float* __restrict__ wg,      // (256,128) f32
    const float* __restrict__ gg, const float* __restrict__ btg,
    const float* __restrict__ mng, const float* __restrict__ vrg,
    const char* __restrict__ wsg,      // prep_rel output
    float* __restrict__ outg)          // (2048,128,128) f32 out
{
  __shared__ __align__(64) char L[LDS_BYTES];
  const int tid  = threadIdx.x;
  // XCD swizzle: 8 head-blocks of one batch share an XCD
  const unsigned bid = blockIdx.x;
  const int xcd = bid & 7;
  const unsigned li = bid >> 3;
  const int h = (int)(li & 7);
  const int b = (int)((li >> 3) * 8 + (unsigned)xcd);
  const int w    = tid >> 6;          // wave 0..7, owns d-rows [w*16, w*16+16)
  const int lane = tid & 63;
  const int q    = lane >> 4;
  const int m16  = lane & 15;
  const int qbase = lane & 48;

  // ---------- P0: copy rel tables from ws + stage W hi/lo + BN params ----------
  #pragma unroll
  for (int u0 = 0; u0 < 1280; u0 += 512) {       // EQKH+EQKL: 20480 B
    int u = u0 + tid;
    if (u < 1280) *(float4v*)(L + u * 16) = *(const float4v*)(wsg + u * 16);
  }
  {                                               // EVR: 8960 B
    *(float4v*)(L + OFF_EVR + tid * 16) = *(const float4v*)(wsg + 20480 + tid * 16);
    if (tid < 48) {
      int u2 = 512 + tid;
      *(float4v*)(L + OFF_EVR + u2 * 16) = *(const float4v*)(wsg + 20480 + u2 * 16);
    }
  }
  {                                               // W hi/lo staged ONCE (shared by 8 waves)
    int o = tid >> 4, c0 = (tid & 15) * 8;
    const float* wrow = wg + (o * 8 + h) * 128 + c0;
    short8 hi, lo;
    #pragma unroll
    for (int k = 0; k < 8; ++k) {
      float f = wrow[k];
      ushort_t hh = f2bf(f);
      hi[k] = (short)hh; lo[k] = (short)f2bf(f - bf2f(hh));
    }
    *(short8*)(L + OFF_WH + o * 272 + c0 * 2) = hi;
    *(short8*)(L + OFF_WL + o * 272 + c0 * 2) = lo;
  }
  if (tid < 32) {
    int og = tid * 8 + h;
    float inv = gg[og] / sqrtf(vrg[og] + 1e-5f);
    ((float*)(L + OFF_IB))[tid * 2]     = inv;
    ((float*)(L + OFF_IB))[tid * 2 + 1] = btg[og] - mng[og] * inv;
  }
  __syncthreads();

  // ---------- P1: conv + BN (hi/lo split); W from LDS ----------
  float4v acc0 = {0,0,0,0}, acc1 = {0,0,0,0};
  {
    const int d = w * 16 + m16;
    const float* xb = xg + (size_t)b * 16384 + d;
    #pragma unroll
    for (int cc = 0; cc < 4; ++cc) {
      const int cb = cc * 32;
      short8 xh, xl;
      #pragma unroll
      for (int jj = 0; jj < 8; ++jj) {
        float xv = xb[(cb + q * 8 + jj) * 128];
        ushort_t hh = f2bf(xv);
        xh[jj] = (short)hh; xl[jj] = (short)f2bf(xv - bf2f(hh));
      }
      const char* wbh = L + OFF_WH + m16 * 272 + (cb + q * 8) * 2;
      const char* wbl = L + OFF_WL + m16 * 272 + (cb + q * 8) * 2;
      short8 wh0 = *(const short8*)(wbh);
      short8 wh1 = *(const short8*)(wbh + 16 * 272);
      short8 wl0 = *(const short8*)(wbl);
      short8 wl1 = *(const short8*)(wbl + 16 * 272);
      acc0 = MFMA16(wh0, xh, acc0);
      acc0 = MFMA16(wl0, xh, acc0);
      acc0 = MFMA16(wh0, xl, acc0);
      acc1 = MFMA16(wh1, xh, acc1);
      acc1 = MFMA16(wl1, xh, acc1);
      acc1 = MFMA16(wh1, xl, acc1);
    }
  }
  __syncthreads();   // all W reads done; QH/QL may now alias W region

  {
    const int d = w * 16 + m16;
    const float* ib = (const float*)(L + OFF_IB);
    {  // o in [0,16): QH/QL (+KT = k*log2e at QH+32)
      const float sc = (q < 2) ? 0.08838834764831845f : 1.0f;
      short4v hi4, lo4, kt4;
      #pragma unroll
      for (int r = 0; r < 4; ++r) {
        int o = q * 4 + r;
        float y = (acc0[r] * ib[o * 2] + ib[o * 2 + 1]) * sc;
        ushort_t hh = f2bf(y);
        hi4[r] = (short)hh; lo4[r] = (short)f2bf(y - bf2f(hh));
        kt4[r] = (short)f2bf(y * LOG2E);
      }
      *(short4v*)(L + OFF_QH + d * 48 + q * 8) = hi4;
      *(short4v*)(L + OFF_QL + d * 40 + q * 8) = lo4;
      if (q >= 2) *(short4v*)(L + OFF_QH + d * 48 + 32 + (q - 2) * 8) = kt4;
    }
    #pragma unroll
    for (int r = 0; r < 4; ++r) {  // o in [16,32): V
      int o = 16 + q * 4 + r;
      float y = acc1[r] * ib[o * 2] + ib[o * 2 + 1];
      *(ushort_t*)(L + OFF_V + (q * 4 + r) * 272 + d * 2) = f2bf(y);
    }
  }
  __syncthreads();

  // ---------- Score phase: D[d][tt] fully in registers. tt = j + 15 - (d&15). ----------
  const int toff = 112 - w * 16;               // rel row t = tt + toff
  const int rowd = w * 16 + m16;
  short8 A1 = *(const short8*)(L + OFF_QH + rowd * 48 + (q & 1) * 16);    // [qk_hi|qk_hi]
  short8 A2 = sel8(q < 2, ld8_2x4(L + OFF_QL + rowd * 40 + (q & 1) * 16)); // [qk_lo|0]
  float4v sc[9];
  {
    const char* eb = L + ((q < 2) ? OFF_EQKH : OFF_EQKL) + (q & 1) * 16;
    #pragma unroll
    for (int tk = 0; tk < 9; ++tk) {     // t-part: rel_hi*qk_hi + rel_lo*qk_hi + rel_hi*qk_lo
      short8 b1 = ld8_2x4(eb + (tk * 16 + m16 + toff) * 40);
      float4v z = {0,0,0,0};
      float4v c = MFMA16(A1, b1, z);
      sc[tk] = MFMA16(A2, b1, c);
    }
  }
  // dots in (d,j) coords, lane-rotated into skew registers via __shfl + fmac masks
  float mk[4], mkb[4];
  {
    const int base0 = m16 + q * 4 + 1;   // source lane seed: (m16 - sigma) mod 16
    #pragma unroll
    for (int r = 0; r < 4; ++r) {
      bool ge = ((base0 + r) & 16) != 0; // receiving lane m16 >= sigma  (no wrap)
      mk[r]  = ge ? 1.0f : 0.0f;
      mkb[r] = 1.0f - mk[r];
    }
    short8 Ad = sel8(q == 0, A1);        // q_s hi, k<8; zeros make bk's k>=8 content irrelevant
    #pragma unroll
    for (int jt = 0; jt < 8; ++jt) {
      short8 bk = *(const short8*)(L + OFF_QH + (jt * 16 + m16) * 48 + 32);
      float4v z = {0,0,0,0};
      float4v c = MFMA16(Ad, bk, z);
      #pragma unroll
      for (int r = 0; r < 4; ++r) {
        int sl = ((base0 + r) & 15) | qbase;   // absolute source lane (same quad)
        float rot = __shfl(c[r], sl, 64);
        sc[jt][r]     += rot * mk[r];
        sc[jt + 1][r] += rot * mkb[r];
      }
    }
  }
  __syncthreads();   // all score-phase LDS reads done; ATT may now alias EQK/QH/QL

  // ---------- softmax: NO max pass (scores bounded << 127 in log2 domain), ----------
  // ---------- NO sum reduce (row sum computed by MFMA in the kv GEMM)      ----------
  {
    #pragma unroll
    for (int r = 0; r < 4; ++r) {
      float e[9];
      #pragma unroll
      for (int tk = 0; tk < 9; ++tk) e[tk] = __builtin_exp2f(sc[tk][r]);
      e[0] *= mk[r];                    // invalid skew cells -> 0
      e[8] *= mkb[r];
      const int dd = w * 16 + q * 4 + r;
      const size_t rowp = (size_t)(L + OFF_ATT) + (size_t)dd * 288;
      const size_t sw = ((dd >> 2) & 3) << 4;
      #pragma unroll
      for (int tk = 0; tk < 9; ++tk)
        *(ushort_t*)((rowp + (tk * 16 + m16) * 2) ^ sw) = f2bf(e[tk]);
    }
  }
  __syncthreads();   // order ATT stores before ATT reads

  // ---------- out+kv GEMM + MFMA row-sum: wave-private 16x16 tile ----------
  {
    float4v acc  = {0,0,0,0};
    float4v accs = {0,0,0,0};
    const short8 ones = {16256,16256,16256,16256,16256,16256,16256,16256}; // bf16 1.0
    const char* evrow = L + OFF_EVR + m16 * 560;
    const char* vrow  = L + OFF_V + m16 * 272;
    const size_t abase = (size_t)(L + OFF_ATT) + (size_t)rowd * 288;
    const size_t swz = ((rowd >> 2) & 3) << 4;
    #pragma unroll
    for (int kk = 0; kk < 4; ++kk) {     // out: straight attn gathered from skew rows
      short8 af;
      #pragma unroll
      for (int jj = 0; jj < 8; ++jj) {
        int ttg = kk * 32 + q * 8 + jj + 15 - m16;   // in [0,142]
        af[jj] = *(const short*)((abase + ttg * 2) ^ swz);
      }
      short8 bf = *(const short8*)(vrow + (kk * 32 + q * 8) * 2);
      acc = MFMA16(af, bf, acc);
    }
    #pragma unroll
    for (int kk = 0; kk < 5; ++kk) {     // kv: skew attn x rel_v(t = tt + toff); + row sum
      short8 af;
      if (kk == 4 && q >= 2) af = (short8){0,0,0,0,0,0,0,0};
      else af = *(const short8*)((abase + (kk * 32 + q * 8) * 2) ^ swz);
      short8 bf = *(const short8*)(evrow + (toff + kk * 32 + q * 8) * 2);
      acc  = MFMA16(af, bf, acc);
      accs = MFMA16(af, ones, accs);     // s[d] lands in the same acc layout
    }
    #pragma unroll
    for (int r = 0; r < 4; ++r)          // deferred normalization
      acc[r] *= __builtin_amdgcn_rcpf(accs[r]);
    float* op = outg + (size_t)b * 16384 + (h * 16 + m16) * 128 + w * 16 + q * 4;
    *(float4v*)op = acc;
  }
}

extern "C" void kernel_launch(void* const* d_in, const int* in_sizes, int n_in,
                              void* d_out, int out_size, void* d_ws, size_t ws_size,
                              hipStream_t stream) {
  const float* xg   = (const float*)d_in[0];
  const float* wg   = (const float*)d_in[1];
  const float* gg   = (const float*)d_in[2];
  const float* btg  = (const float*)d_in[3];
  const float* mng  = (const float*)d_in[4];
  const float* vrg  = (const float*)d_in[5];
  const float* relg = (const float*)d_in[6];
  float* outg = (float*)d_out;
  char* ws = (char*)d_ws;
  prep_rel<<<dim3(17), dim3(512), 0, stream>>>(relg, ws);
  axial_fused<<<dim3(16384), dim3(512), 0, stream>>>(xg, wg, gg, btg, mng, vrg, ws, outg);
}